// Round 11
// baseline (79.184 us; speedup 1.0000x reference)
//
#include <hip/hip_runtime.h>
#include <hip/hip_bf16.h>
#include <stdint.h>

typedef short bf16x8 __attribute__((ext_vector_type(8)));
typedef float f32x4 __attribute__((ext_vector_type(4)));
typedef float f32x2 __attribute__((ext_vector_type(2)));

#define D  512
#define NB 4096
#define NT 8192

__device__ __forceinline__ unsigned short f2bf(float f) {
    __hip_bfloat16 h = __float2bfloat16(f);
    return *reinterpret_cast<unsigned short*>(&h);
}

// Fused fp32->bf16 convert + row squared-norm for BOTH inputs; x rows also
// write the fp32 passthrough (output 0). One wave per row. HBM-floor bound.
__global__ __launch_bounds__(256) void prep_kernel(
    const float* __restrict__ x, const float* __restrict__ y,
    unsigned short* __restrict__ xb, unsigned short* __restrict__ yb,
    float* __restrict__ x2, float* __restrict__ y2, float* __restrict__ copy)
{
    const int grow = blockIdx.x * 4 + (threadIdx.x >> 6);
    const int lane = threadIdx.x & 63;
    const bool isX = grow < NB;
    const int row  = isX ? grow : grow - NB;
    const float* src = isX ? x : y;
    unsigned short* dst = isX ? xb : yb;
    float* norms = isX ? x2 : y2;

    const float4* rp = reinterpret_cast<const float4*>(src + (size_t)row * D);
    float4 v0 = rp[lane * 2];
    float4 v1 = rp[lane * 2 + 1];
    if (isX) {
        float4* cp = reinterpret_cast<float4*>(copy + (size_t)row * D);
        cp[lane * 2]     = v0;
        cp[lane * 2 + 1] = v1;
    }
    float s = v0.x*v0.x + v0.y*v0.y + v0.z*v0.z + v0.w*v0.w
            + v1.x*v1.x + v1.y*v1.y + v1.z*v1.z + v1.w*v1.w;
    union { unsigned short h[8]; int4 v; } u;
    u.h[0] = f2bf(v0.x); u.h[1] = f2bf(v0.y); u.h[2] = f2bf(v0.z); u.h[3] = f2bf(v0.w);
    u.h[4] = f2bf(v1.x); u.h[5] = f2bf(v1.y); u.h[6] = f2bf(v1.z); u.h[7] = f2bf(v1.w);
    reinterpret_cast<int4*>(dst + (size_t)row * D)[lane] = u.v;
    #pragma unroll
    for (int off = 32; off > 0; off >>= 1) s += __shfl_xor(s, off);
    if (lane == 0) norms[row] = s;
}

// Wave-specialized persistent GEMM: 256 blocks (1/CU), 6 waves each
// (w0-3 compute = exact R10 engine on 128x256 tiles, BK=32, 3 rotating
// stage bufs, counted vmcnt; w4-5 store). Each block does 4 col-adjacent
// tiles. Compute epilogue writes sim (bf16) to a 64 KB LDS xfer buffer;
// store waves expand bf16->f32 (bit-shift, exact) and stream tile t-1's
// 128 KB to HBM during tile t's main loop. Store waves' vmcnt FIFO holds
// ONLY stores (never waited), so backpressure -- not forced drains --
// paces the block to HBM-write rate with MFMA hidden under it (fixes the
// R3/R9 single-FIFO failure). All s_barriers are shared statements
// outside role branches: 17 per tile + 1 final, both roles.
// LDS: stage 3x24 KiB @0 + xfer 128x256 bf16 @36864 = 136 KiB -> 1 blk/CU.
__global__ __launch_bounds__(384, 1) void gemm_sim_kernel(
    const unsigned short* __restrict__ X, const unsigned short* __restrict__ Y,
    const float* __restrict__ x2, const float* __restrict__ y2,
    float* __restrict__ out)
{
    __shared__ alignas(16) unsigned short lds[69632];   // 136 KiB

    const int t    = threadIdx.x;
    const int lane = t & 63;
    const int w    = t >> 6;                 // 0..5
    const bool isCompute = (w < 4);

    // 256 blocks: per XCD 16 rowTiles x 2 colGroups (A 2MB + B 2MB = L2-fit).
    const int bid = blockIdx.x;
    const int xcd = bid & 7;
    const int idx = bid >> 3;                           // 0..31
    const int rowBase   = ((xcd & 1) * 16 + (idx & 15)) * 128;
    const int colGroup0 = ((xcd >> 1) * 2 + (idx >> 4)) * 1024;  // 4 tiles

    // Staging map (compute waves, t<256): thread covers 16 B at LDS off t*8
    // (+L*2048). Chunk-XOR swizzle (rule #21) pre-applied on the source.
    const int swz = ((t & 3) ^ ((t >> 3) & 3)) * 8;
    const unsigned short* gA = X + (size_t)(rowBase   + (t >> 2)) * D + swz;
    const unsigned short* gB = Y + (size_t)(colGroup0 + (t >> 2)) * D + swz;

    // Fragment-read constants.
    const int cread = ((lane >> 4) ^ ((lane >> 1) & 3)) * 8;
    const int aoff = (lane & 15) * 32 + cread;
    const int boff = 4096 + (w * 64 + (lane & 15)) * 32 + cread;

    const int col_l0 = w * 64 + (lane & 15);       // tile-local col (compute)
    const int row_l0 = (lane >> 4) << 2;           // tile-local row base
    unsigned short* xf = lds + 36864;
    const int g = (w - 4) * 64 + lane;             // store-wave lane 0..127

    f32x4 acc[8][4] = {};

    // Norm preloads (static indices; retired by prologue vmcnt(6)).
    float x2v[32], y2v[16];
    if (isCompute) {
        #pragma unroll
        for (int mi = 0; mi < 8; ++mi)
            #pragma unroll
            for (int q = 0; q < 4; ++q)
                x2v[mi * 4 + q] = x2[rowBase + row_l0 + (mi >> 2) * 64 + (mi & 3) * 16 + q];
        #pragma unroll
        for (int tl = 0; tl < 4; ++tl)
            #pragma unroll
            for (int n = 0; n < 4; ++n)
                y2v[tl * 4 + n] = y2[colGroup0 + tl * 256 + col_l0 + n * 16];
    }

#define BAR() do { asm volatile("" ::: "memory"); __builtin_amdgcn_s_barrier(); \
                   asm volatile("" ::: "memory"); } while (0)

#define STAGE_A(BUF, KT) do { \
    _Pragma("unroll") \
    for (int L = 0; L < 2; ++L) \
        __builtin_amdgcn_global_load_lds( \
            (const __attribute__((address_space(1))) void*)(gA + (size_t)L * 64 * D + (KT) * 32), \
            (__attribute__((address_space(3))) void*)(lds + (BUF) * 12288 + t * 8 + L * 2048), 16, 0, 0); \
} while (0)

#define STAGE_B(BUF, KT, TL) do { \
    _Pragma("unroll") \
    for (int L = 0; L < 4; ++L) \
        __builtin_amdgcn_global_load_lds( \
            (const __attribute__((address_space(1))) void*)(gB + (size_t)(TL) * 256 * D + (size_t)L * 64 * D + (KT) * 32), \
            (__attribute__((address_space(3))) void*)(lds + (BUF) * 12288 + 4096 + t * 8 + L * 2048), 16, 0, 0); \
} while (0)

#define KTBODY(TL, KT) do { \
    if (isCompute) { \
        bf16x8 _a[2][4], _b[4]; \
        _Pragma("unroll") \
        for (int n = 0; n < 4; ++n) \
            _b[n] = *(const bf16x8*)(lds + ((KT) % 3) * 12288 + boff + n * 512); \
        _Pragma("unroll") \
        for (int h = 0; h < 2; ++h) \
            _Pragma("unroll") \
            for (int m = 0; m < 4; ++m) \
                _a[h][m] = *(const bf16x8*)(lds + ((KT) % 3) * 12288 + aoff + h * 2048 + m * 512); \
        if ((KT) + 2 < 16) { \
            STAGE_A(((KT) + 2) % 3, (KT) + 2); \
            STAGE_B(((KT) + 2) % 3, (KT) + 2, TL); \
        } \
        __builtin_amdgcn_s_setprio(1); \
        _Pragma("unroll") \
        for (int h = 0; h < 2; ++h) \
            _Pragma("unroll") \
            for (int m = 0; m < 4; ++m) \
                _Pragma("unroll") \
                for (int n = 0; n < 4; ++n) \
                    acc[h * 4 + m][n] = __builtin_amdgcn_mfma_f32_16x16x32_bf16( \
                        _a[h][m], _b[n], acc[h * 4 + m][n], 0, 0, 0); \
        __builtin_amdgcn_s_setprio(0); \
        __builtin_amdgcn_sched_barrier(0); \
        if ((KT) < 14)       { asm volatile("s_waitcnt vmcnt(6)" ::: "memory"); } \
        else if ((KT) == 14) { asm volatile("s_waitcnt vmcnt(0)" ::: "memory"); } \
    } else if ((TL) > 0) { \
        const uint32_t* xfu = (const uint32_t*)xf; \
        _Pragma("unroll") \
        for (int j = 0; j < 8; ++j) { \
            const int r = (KT) * 8 + j; \
            uint32_t u = xfu[r * 128 + g]; \
            f32x2 v; \
            v.x = __uint_as_float(u << 16); \
            v.y = __uint_as_float(u & 0xffff0000u); \
            __builtin_nontemporal_store(v, \
                (f32x2*)(out + (size_t)(rowBase + r) * NT + colGroup0 + ((TL) - 1) * 256 + 2 * g)); \
        } \
    } \
    BAR(); \
} while (0)

#define TILE(TL) do { \
    BAR();  /* H: xfer(TL-1) published + stage kt0 landed */ \
    KTBODY(TL, 0);  KTBODY(TL, 1);  KTBODY(TL, 2);  KTBODY(TL, 3); \
    KTBODY(TL, 4);  KTBODY(TL, 5);  KTBODY(TL, 6);  KTBODY(TL, 7); \
    KTBODY(TL, 8);  KTBODY(TL, 9);  KTBODY(TL, 10); KTBODY(TL, 11); \
    KTBODY(TL, 12); KTBODY(TL, 13); KTBODY(TL, 14); KTBODY(TL, 15); \
    if (isCompute) { \
        if ((TL) < 3) { \
            STAGE_A(0, 0); STAGE_B(0, 0, (TL) + 1); \
            STAGE_A(1, 1); STAGE_B(1, 1, (TL) + 1); \
        } \
        _Pragma("unroll") \
        for (int mi = 0; mi < 8; ++mi) { \
            const int rb = row_l0 + (mi >> 2) * 64 + (mi & 3) * 16; \
            _Pragma("unroll") \
            for (int q = 0; q < 4; ++q) { \
                _Pragma("unroll") \
                for (int n = 0; n < 4; ++n) { \
                    float sq = fmaxf(x2v[mi * 4 + q] + y2v[(TL) * 4 + n] \
                                     - 2.0f * acc[mi][n][q], 0.0f); \
                    xf[(rb + q) * 256 + col_l0 + n * 16] = \
                        f2bf(fminf(rsqrtf(sq), 1.0e6f)); \
                } \
            } \
        } \
        _Pragma("unroll") \
        for (int mi = 0; mi < 8; ++mi) \
            _Pragma("unroll") \
            for (int n = 0; n < 4; ++n) \
                acc[mi][n] = (f32x4){0.f, 0.f, 0.f, 0.f}; \
        asm volatile("s_waitcnt lgkmcnt(0)" ::: "memory"); \
        if ((TL) < 3) { asm volatile("s_waitcnt vmcnt(6)" ::: "memory"); } \
    } \
} while (0)

    // Prologue: stage tile0 kt0+kt1; vmcnt(6) retires norm preloads + kt0.
    if (isCompute) {
        STAGE_A(0, 0); STAGE_B(0, 0, 0);
        STAGE_A(1, 1); STAGE_B(1, 1, 0);
        asm volatile("s_waitcnt vmcnt(6)" ::: "memory");
    }

    TILE(0); TILE(1); TILE(2); TILE(3);
    BAR();   // publish xfer(3)

    // Tail: store waves flush tile 3 (no barriers past this point).
    if (!isCompute) {
        const uint32_t* xfu = (const uint32_t*)xf;
        for (int r = 0; r < 128; ++r) {
            uint32_t u = xfu[r * 128 + g];
            f32x2 v;
            v.x = __uint_as_float(u << 16);
            v.y = __uint_as_float(u & 0xffff0000u);
            __builtin_nontemporal_store(v,
                (f32x2*)(out + (size_t)(rowBase + r) * NT + colGroup0 + 768 + 2 * g));
        }
    }
#undef TILE
#undef KTBODY
#undef STAGE_A
#undef STAGE_B
#undef BAR
}

extern "C" void kernel_launch(void* const* d_in, const int* in_sizes, int n_in,
                              void* d_out, int out_size, void* d_ws, size_t ws_size,
                              hipStream_t stream)
{
    const float* x = (const float*)d_in[0];
    const float* y = (const float*)d_in[1];
    float* out = (float*)d_out;
    char* ws = (char*)d_ws;

    unsigned short* xb = (unsigned short*)ws;                 // 4 MB
    unsigned short* yb = (unsigned short*)(ws + (4u << 20));  // 8 MB
    float* x2 = (float*)(ws + (12u << 20));                   // 16 KB
    float* y2 = (float*)(ws + (12u << 20) + 4 * NB);          // 32 KB

    prep_kernel<<<(NB + NT) / 4, 256, 0, stream>>>(x, y, xb, yb, x2, y2, out);
    gemm_sim_kernel<<<256, 384, 0, stream>>>(xb, yb, x2, y2, out + (size_t)NB * D);
}

// Round 12
// 72.609 us; speedup vs baseline: 1.0906x; 1.0906x over previous
//
#include <hip/hip_runtime.h>
#include <hip/hip_bf16.h>
#include <stdint.h>

typedef short bf16x8 __attribute__((ext_vector_type(8)));
typedef float f32x4 __attribute__((ext_vector_type(4)));
typedef float f32x2 __attribute__((ext_vector_type(2)));

#define D  512
#define NB 4096
#define NT 8192
#define XS 264   // xfer row stride (ushorts), padded vs 256 to break bank alignment

__device__ __forceinline__ unsigned short f2bf(float f) {
    __hip_bfloat16 h = __float2bfloat16(f);
    return *reinterpret_cast<unsigned short*>(&h);
}

// Fused fp32->bf16 convert + row squared-norm for BOTH inputs; x rows also
// write the fp32 passthrough (output 0). One wave per row. HBM-floor bound.
__global__ __launch_bounds__(256) void prep_kernel(
    const float* __restrict__ x, const float* __restrict__ y,
    unsigned short* __restrict__ xb, unsigned short* __restrict__ yb,
    float* __restrict__ x2, float* __restrict__ y2, float* __restrict__ copy)
{
    const int grow = blockIdx.x * 4 + (threadIdx.x >> 6);
    const int lane = threadIdx.x & 63;
    const bool isX = grow < NB;
    const int row  = isX ? grow : grow - NB;
    const float* src = isX ? x : y;
    unsigned short* dst = isX ? xb : yb;
    float* norms = isX ? x2 : y2;

    const float4* rp = reinterpret_cast<const float4*>(src + (size_t)row * D);
    float4 v0 = rp[lane * 2];
    float4 v1 = rp[lane * 2 + 1];
    if (isX) {
        float4* cp = reinterpret_cast<float4*>(copy + (size_t)row * D);
        cp[lane * 2]     = v0;
        cp[lane * 2 + 1] = v1;
    }
    float s = v0.x*v0.x + v0.y*v0.y + v0.z*v0.z + v0.w*v0.w
            + v1.x*v1.x + v1.y*v1.y + v1.z*v1.z + v1.w*v1.w;
    union { unsigned short h[8]; int4 v; } u;
    u.h[0] = f2bf(v0.x); u.h[1] = f2bf(v0.y); u.h[2] = f2bf(v0.z); u.h[3] = f2bf(v0.w);
    u.h[4] = f2bf(v1.x); u.h[5] = f2bf(v1.y); u.h[6] = f2bf(v1.z); u.h[7] = f2bf(v1.w);
    reinterpret_cast<int4*>(dst + (size_t)row * D)[lane] = u.v;
    #pragma unroll
    for (int off = 32; off > 0; off >>= 1) s += __shfl_xor(s, off);
    if (lane == 0) norms[row] = s;
}

// Wave-specialized persistent GEMM v2 (R11 skeleton + 2 compute waves/SIMD):
// 256 blocks (1/CU), 10 waves = 8 compute (2Mx4N, wave-tile 64x64) + 2 store.
// 4 col-adjacent 128x256 tiles per block, BK=32, 3 rotating stage bufs,
// counted vmcnt (loads-only FIFO in compute waves; stores-only FIFO in store
// waves -> no forced drains). Compute epilogue drops sim (bf16) into a padded
// LDS xfer buffer; store waves expand bf16->f32 and nt-stream tile t-1 during
// tile t's loop. All s_barriers shared between roles (R11-audited).
// LDS: stage 3x24 KiB + xfer 128xXS u16 = 138 KiB -> 1 block/CU.
__global__ __launch_bounds__(640, 1) void gemm_sim_kernel(
    const unsigned short* __restrict__ X, const unsigned short* __restrict__ Y,
    const float* __restrict__ x2, const float* __restrict__ y2,
    float* __restrict__ out)
{
    __shared__ alignas(16) unsigned short lds[36864 + 128 * XS];

    const int t    = threadIdx.x;
    const int lane = t & 63;
    const int w    = t >> 6;                 // 0..9
    const bool isCompute = (w < 8);
    const int wr = (w >> 2) & 1;             // compute: row half (64 rows)
    const int wc = w & 3;                    // compute: col quarter (64 cols)

    // 256 blocks: per XCD 16 rowTiles x 2 colGroups (A 2MB + B 2MB = L2-fit).
    const int bid = blockIdx.x;
    const int xcd = bid & 7;
    const int idx = bid >> 3;                           // 0..31
    const int rowBase   = ((xcd & 1) * 16 + (idx & 15)) * 128;
    const int colGroup0 = ((xcd >> 1) * 2 + (idx >> 4)) * 1024;  // 4 tiles

    // Staging map (threads 0..255 only): 16 B at LDS off t*8 (+L*2048).
    // Chunk-XOR swizzle (rule #21) pre-applied on the global source.
    const int swz = ((t & 3) ^ ((t >> 3) & 3)) * 8;
    const unsigned short* gA = X + (size_t)(rowBase   + ((t & 255) >> 2)) * D + swz;
    const unsigned short* gB = Y + (size_t)(colGroup0 + ((t & 255) >> 2)) * D + swz;

    // Fragment-read constants (compute waves).
    const int cread = ((lane >> 4) ^ ((lane >> 1) & 3)) * 8;
    const int aoff = (wr * 64 + (lane & 15)) * 32 + cread;
    const int boff = 4096 + (wc * 64 + (lane & 15)) * 32 + cread;

    const int col_l0 = wc * 64 + (lane & 15);      // tile-local col (compute)
    const int row_l0 = wr * 64 + ((lane >> 4) << 2);  // tile-local row base
    unsigned short* xf = lds + 36864;
    const int g = (w - 8) * 64 + lane;             // store-wave lane 0..127

    f32x4 acc[4][4] = {};

    // Norm preloads (static indices; drained by the first vmcnt checkpoint).
    float x2v[16], y2v[16];
    if (isCompute) {
        #pragma unroll
        for (int mi = 0; mi < 4; ++mi)
            #pragma unroll
            for (int q = 0; q < 4; ++q)
                x2v[mi * 4 + q] = x2[rowBase + row_l0 + mi * 16 + q];
        #pragma unroll
        for (int tl = 0; tl < 4; ++tl)
            #pragma unroll
            for (int n = 0; n < 4; ++n)
                y2v[tl * 4 + n] = y2[colGroup0 + tl * 256 + col_l0 + n * 16];
    }

#define BAR() do { asm volatile("" ::: "memory"); __builtin_amdgcn_s_barrier(); \
                   asm volatile("" ::: "memory"); } while (0)

#define STAGE_A(BUF, KT) do { \
    _Pragma("unroll") \
    for (int L = 0; L < 2; ++L) \
        __builtin_amdgcn_global_load_lds( \
            (const __attribute__((address_space(1))) void*)(gA + (size_t)L * 64 * D + (KT) * 32), \
            (__attribute__((address_space(3))) void*)(lds + (BUF) * 12288 + t * 8 + L * 2048), 16, 0, 0); \
} while (0)

#define STAGE_B(BUF, KT, TL) do { \
    _Pragma("unroll") \
    for (int L = 0; L < 4; ++L) \
        __builtin_amdgcn_global_load_lds( \
            (const __attribute__((address_space(1))) void*)(gB + (size_t)(TL) * 256 * D + (size_t)L * 64 * D + (KT) * 32), \
            (__attribute__((address_space(3))) void*)(lds + (BUF) * 12288 + 4096 + t * 8 + L * 2048), 16, 0, 0); \
} while (0)

#define KTBODY(TL, KT) do { \
    if (isCompute) { \
        bf16x8 _a[4], _b[4]; \
        _Pragma("unroll") \
        for (int n = 0; n < 4; ++n) \
            _b[n] = *(const bf16x8*)(lds + ((KT) % 3) * 12288 + boff + n * 512); \
        _Pragma("unroll") \
        for (int m = 0; m < 4; ++m) \
            _a[m] = *(const bf16x8*)(lds + ((KT) % 3) * 12288 + aoff + m * 512); \
        if ((KT) + 2 < 16 && t < 256) { \
            STAGE_A(((KT) + 2) % 3, (KT) + 2); \
            STAGE_B(((KT) + 2) % 3, (KT) + 2, TL); \
        } \
        __builtin_amdgcn_s_setprio(1); \
        _Pragma("unroll") \
        for (int m = 0; m < 4; ++m) \
            _Pragma("unroll") \
            for (int n = 0; n < 4; ++n) \
                acc[m][n] = __builtin_amdgcn_mfma_f32_16x16x32_bf16( \
                    _a[m], _b[n], acc[m][n], 0, 0, 0); \
        __builtin_amdgcn_s_setprio(0); \
        __builtin_amdgcn_sched_barrier(0); \
        if ((KT) < 14)       { asm volatile("s_waitcnt vmcnt(6)" ::: "memory"); } \
        else if ((KT) == 14) { asm volatile("s_waitcnt vmcnt(0)" ::: "memory"); } \
    } else if ((TL) > 0) { \
        const uint32_t* xfu = (const uint32_t*)xf; \
        _Pragma("unroll") \
        for (int j = 0; j < 8; ++j) { \
            const int r = (KT) * 8 + j; \
            uint32_t u = xfu[r * (XS / 2) + g]; \
            f32x2 v; \
            v.x = __uint_as_float(u << 16); \
            v.y = __uint_as_float(u & 0xffff0000u); \
            __builtin_nontemporal_store(v, \
                (f32x2*)(out + (size_t)(rowBase + r) * NT + colGroup0 + ((TL) - 1) * 256 + 2 * g)); \
        } \
    } \
    BAR(); \
} while (0)

#define TILE(TL) do { \
    BAR();  /* xfer(TL-1) published + stage kt0 landed */ \
    KTBODY(TL, 0);  KTBODY(TL, 1);  KTBODY(TL, 2);  KTBODY(TL, 3); \
    KTBODY(TL, 4);  KTBODY(TL, 5);  KTBODY(TL, 6);  KTBODY(TL, 7); \
    KTBODY(TL, 8);  KTBODY(TL, 9);  KTBODY(TL, 10); KTBODY(TL, 11); \
    KTBODY(TL, 12); KTBODY(TL, 13); KTBODY(TL, 14); KTBODY(TL, 15); \
    if (isCompute) { \
        if ((TL) < 3 && t < 256) { \
            STAGE_A(0, 0); STAGE_B(0, 0, (TL) + 1); \
            STAGE_A(1, 1); STAGE_B(1, 1, (TL) + 1); \
        } \
        _Pragma("unroll") \
        for (int mi = 0; mi < 4; ++mi) { \
            _Pragma("unroll") \
            for (int q = 0; q < 4; ++q) { \
                _Pragma("unroll") \
                for (int n = 0; n < 4; ++n) { \
                    float sq = fmaxf(x2v[mi * 4 + q] + y2v[(TL) * 4 + n] \
                                     - 2.0f * acc[mi][n][q], 0.0f); \
                    xf[(row_l0 + mi * 16 + q) * XS + col_l0 + n * 16] = \
                        f2bf(fminf(rsqrtf(sq), 1.0e6f)); \
                } \
            } \
        } \
        _Pragma("unroll") \
        for (int mi = 0; mi < 4; ++mi) \
            _Pragma("unroll") \
            for (int n = 0; n < 4; ++n) \
                acc[mi][n] = (f32x4){0.f, 0.f, 0.f, 0.f}; \
        asm volatile("s_waitcnt lgkmcnt(0)" ::: "memory"); \
        if ((TL) < 3) { asm volatile("s_waitcnt vmcnt(6)" ::: "memory"); } \
    } \
} while (0)

    // Prologue: stage tile0 kt0+kt1; vmcnt(6) retires norm preloads + kt0.
    if (isCompute && t < 256) {
        STAGE_A(0, 0); STAGE_B(0, 0, 0);
        STAGE_A(1, 1); STAGE_B(1, 1, 0);
    }
    if (isCompute) { asm volatile("s_waitcnt vmcnt(6)" ::: "memory"); }

    TILE(0); TILE(1); TILE(2); TILE(3);
    BAR();   // publish xfer(3)

    // Tail: store waves flush tile 3 (no barriers past this point).
    if (!isCompute) {
        const uint32_t* xfu = (const uint32_t*)xf;
        for (int r = 0; r < 128; ++r) {
            uint32_t u = xfu[r * (XS / 2) + g];
            f32x2 v;
            v.x = __uint_as_float(u << 16);
            v.y = __uint_as_float(u & 0xffff0000u);
            __builtin_nontemporal_store(v,
                (f32x2*)(out + (size_t)(rowBase + r) * NT + colGroup0 + 768 + 2 * g));
        }
    }
#undef TILE
#undef KTBODY
#undef STAGE_A
#undef STAGE_B
#undef BAR
}

extern "C" void kernel_launch(void* const* d_in, const int* in_sizes, int n_in,
                              void* d_out, int out_size, void* d_ws, size_t ws_size,
                              hipStream_t stream)
{
    const float* x = (const float*)d_in[0];
    const float* y = (const float*)d_in[1];
    float* out = (float*)d_out;
    char* ws = (char*)d_ws;

    unsigned short* xb = (unsigned short*)ws;                 // 4 MB
    unsigned short* yb = (unsigned short*)(ws + (4u << 20));  // 8 MB
    float* x2 = (float*)(ws + (12u << 20));                   // 16 KB
    float* y2 = (float*)(ws + (12u << 20) + 4 * NB);          // 32 KB

    prep_kernel<<<(NB + NT) / 4, 256, 0, stream>>>(x, y, xb, yb, x2, y2, out);
    gemm_sim_kernel<<<256, 640, 0, stream>>>(xb, yb, x2, y2, out + (size_t)NB * D);
}